// Round 2
// baseline (232.367 us; speedup 1.0000x reference)
//
#include <hip/hip_runtime.h>
#include <hip/hip_bf16.h>

// ---------------------------------------------------------------------------
// MultiHeadedMaskedSelfAttention (B=2,T=2048,C=768,H=12,D=64).
// I/O: float32 (per reference dtypes). Compute: bf16 MFMA with hi/lo
// compensation on the softmax-critical path (x->Q/K and Q.K^T), plain bf16
// elsewhere (V, P.V, output projection).
// Pipeline: prep_x (f32 -> bf16 hi/lo) ; prep_w (transpose + hi/lo split) ;
//           qkv_gemm (3-term hi/lo for Q,K; 1-term for V) ; transpose_v ;
//           attn_fwd (causal online-softmax flash) ; proj_gemm -> f32 out.
// ---------------------------------------------------------------------------

typedef float f32x4 __attribute__((ext_vector_type(4)));
typedef short s16x8 __attribute__((ext_vector_type(8)));

#define MFMA(a, b, c) __builtin_amdgcn_mfma_f32_16x16x32_bf16((a), (b), (c), 0, 0, 0)

constexpr int Bb = 2, Tt = 2048, Cc = 768, Hh = 12, Dd = 64;
constexpr int Mm = Bb * Tt;   // 4096
constexpr int BH = Bb * Hh;   // 24

__device__ __forceinline__ void gload16(const void* g, void* l) {
  __builtin_amdgcn_global_load_lds((const __attribute__((address_space(1))) void*)g,
                                   (__attribute__((address_space(3))) void*)l, 16, 0, 0);
}

__device__ __forceinline__ short f2bfbits(float f) {
  __hip_bfloat16 h = __float2bfloat16(f);
  return __builtin_bit_cast(short, h);
}
__device__ __forceinline__ float bf2f(short s) {
  __hip_bfloat16 h = __builtin_bit_cast(__hip_bfloat16, s);
  return __bfloat162float(h);
}

// ---------------------------------------------------------------------------
// prep_x: x f32 [4096][768] -> Xhi, Xlo bf16. grid(1536), 256 thr, 8 elts/thr.
// ---------------------------------------------------------------------------
__global__ __launch_bounds__(256) void prep_x(const float* __restrict__ x,
                                              __hip_bfloat16* __restrict__ xhi,
                                              __hip_bfloat16* __restrict__ xlo) {
  const size_t i = ((size_t)blockIdx.x * 256 + threadIdx.x) * 8;
  float4 a = *reinterpret_cast<const float4*>(x + i);
  float4 b = *reinterpret_cast<const float4*>(x + i + 4);
  float v[8] = {a.x, a.y, a.z, a.w, b.x, b.y, b.z, b.w};
  s16x8 hi, lo;
#pragma unroll
  for (int j = 0; j < 8; ++j) {
    short h = f2bfbits(v[j]);
    hi[j] = h;
    lo[j] = f2bfbits(v[j] - bf2f(h));
  }
  *reinterpret_cast<s16x8*>((short*)xhi + i) = hi;
  *reinterpret_cast<s16x8*>((short*)xlo + i) = lo;
}

// ---------------------------------------------------------------------------
// prep_w: f32 [768][768] -> transposed bf16. z=0: wq (hi+lo), z=1: wk (hi+lo),
// z=2: wv (hi), z=3: linear (hi). grid (12,12,4), 256 thr, 64x64 tiles.
// ---------------------------------------------------------------------------
__global__ __launch_bounds__(256) void prep_w(
    const float* __restrict__ s0, const float* __restrict__ s1,
    const float* __restrict__ s2, const float* __restrict__ s3,
    __hip_bfloat16* __restrict__ h0, __hip_bfloat16* __restrict__ l0,
    __hip_bfloat16* __restrict__ h1, __hip_bfloat16* __restrict__ l1,
    __hip_bfloat16* __restrict__ h2, __hip_bfloat16* __restrict__ h3) {
  const float* src;
  __hip_bfloat16 *dh, *dl = nullptr;
  switch (blockIdx.z) {
    case 0: src = s0; dh = h0; dl = l0; break;
    case 1: src = s1; dh = h1; dl = l1; break;
    case 2: src = s2; dh = h2; break;
    default: src = s3; dh = h3; break;
  }
  __shared__ float tile[64][65];
  const int r0 = blockIdx.y * 64, c0 = blockIdx.x * 64;
  const int tid = threadIdx.x;
  const int rr = tid >> 4, c4 = (tid & 15) * 4;
#pragma unroll
  for (int it = 0; it < 4; ++it) {
    float4 v = *reinterpret_cast<const float4*>(src + (size_t)(r0 + rr + it * 16) * Cc + c0 + c4);
    tile[rr + it * 16][c4 + 0] = v.x;
    tile[rr + it * 16][c4 + 1] = v.y;
    tile[rr + it * 16][c4 + 2] = v.z;
    tile[rr + it * 16][c4 + 3] = v.w;
  }
  __syncthreads();
#pragma unroll
  for (int it = 0; it < 2; ++it) {
    const int id = tid + it * 256;          // 0..511
    const int n = id >> 3, ch = (id & 7) * 8;
    s16x8 hi, lo;
#pragma unroll
    for (int j = 0; j < 8; ++j) {
      float v = tile[ch + j][n];
      short h = f2bfbits(v);
      hi[j] = h;
      lo[j] = f2bfbits(v - bf2f(h));
    }
    *reinterpret_cast<s16x8*>(dh + (size_t)(c0 + n) * Cc + r0 + ch) = hi;
    if (dl) *reinterpret_cast<s16x8*>(dl + (size_t)(c0 + n) * Cc + r0 + ch) = lo;
  }
}

// ---------------------------------------------------------------------------
// 128x128 GEMM cores. A[M,K] * Bt[N,K]^T, K=768, BK=32, 4 waves.
// Wave w -> 64x64 sub-tile (wr,wc)=(w>>1,w&1); acc[4][4] of 16x16 frags.
// ---------------------------------------------------------------------------
__device__ __forceinline__ void gemm128_core(const __hip_bfloat16* __restrict__ A,
                                             const __hip_bfloat16* __restrict__ Bt,
                                             int m0, int n0,
                                             short* ldsA, short* ldsB,
                                             f32x4 acc[4][4]) {
  const int tid = threadIdx.x;
  const int w = tid >> 6, l = tid & 63;
  const int wr = w >> 1, wc = w & 1;
  const int srow = l >> 2;
  const int scol = (l & 3) << 3;

  for (int kt = 0; kt < Cc / 32; ++kt) {
    const int kk = kt << 5;
#pragma unroll
    for (int i = 0; i < 2; ++i) {
      const int r = (w << 5) + (i << 4);
      gload16(A + (size_t)(m0 + r + srow) * Cc + kk + scol, ldsA + r * 32);
      gload16(Bt + (size_t)(n0 + r + srow) * Cc + kk + scol, ldsB + r * 32);
    }
    __syncthreads();
    s16x8 af[4], bfr[4];
#pragma unroll
    for (int i = 0; i < 4; ++i) {
      af[i]  = *reinterpret_cast<const s16x8*>(ldsA + ((wr << 6) + (i << 4) + (l & 15)) * 32 + ((l >> 4) << 3));
      bfr[i] = *reinterpret_cast<const s16x8*>(ldsB + ((wc << 6) + (i << 4) + (l & 15)) * 32 + ((l >> 4) << 3));
    }
#pragma unroll
    for (int i = 0; i < 4; ++i)
#pragma unroll
      for (int j = 0; j < 4; ++j)
        acc[i][j] = MFMA(af[i], bfr[j], acc[i][j]);
    __syncthreads();
  }
}

// hi/lo compensated: acc += Ahi*Bhi + (lo ? Ahi*Blo + Alo*Bhi : 0)
__device__ __forceinline__ void gemm128_hilo(
    const __hip_bfloat16* __restrict__ Ahi, const __hip_bfloat16* __restrict__ Alo,
    const __hip_bfloat16* __restrict__ Bhi, const __hip_bfloat16* __restrict__ Blo,
    bool lo, int m0, int n0, short* lds, f32x4 acc[4][4]) {
  short* ldsAh = lds;
  short* ldsAl = lds + 4096;
  short* ldsBh = lds + 8192;
  short* ldsBl = lds + 12288;
  const int tid = threadIdx.x;
  const int w = tid >> 6, l = tid & 63;
  const int wr = w >> 1, wc = w & 1;
  const int srow = l >> 2;
  const int scol = (l & 3) << 3;

  for (int kt = 0; kt < Cc / 32; ++kt) {
    const int kk = kt << 5;
#pragma unroll
    for (int i = 0; i < 2; ++i) {
      const int r = (w << 5) + (i << 4);
      const size_t aoff = (size_t)(m0 + r + srow) * Cc + kk + scol;
      const size_t boff = (size_t)(n0 + r + srow) * Cc + kk + scol;
      gload16(Ahi + aoff, ldsAh + r * 32);
      gload16(Bhi + boff, ldsBh + r * 32);
      if (lo) {
        gload16(Alo + aoff, ldsAl + r * 32);
        gload16(Blo + boff, ldsBl + r * 32);
      }
    }
    __syncthreads();
    s16x8 ah[4], bh[4], al[4], bl[4];
#pragma unroll
    for (int i = 0; i < 4; ++i) {
      const int ao = ((wr << 6) + (i << 4) + (l & 15)) * 32 + ((l >> 4) << 3);
      const int bo = ((wc << 6) + (i << 4) + (l & 15)) * 32 + ((l >> 4) << 3);
      ah[i] = *reinterpret_cast<const s16x8*>(ldsAh + ao);
      bh[i] = *reinterpret_cast<const s16x8*>(ldsBh + bo);
      if (lo) {
        al[i] = *reinterpret_cast<const s16x8*>(ldsAl + ao);
        bl[i] = *reinterpret_cast<const s16x8*>(ldsBl + bo);
      }
    }
#pragma unroll
    for (int i = 0; i < 4; ++i)
#pragma unroll
      for (int j = 0; j < 4; ++j)
        acc[i][j] = MFMA(ah[i], bh[j], acc[i][j]);
    if (lo) {
#pragma unroll
      for (int i = 0; i < 4; ++i)
#pragma unroll
        for (int j = 0; j < 4; ++j) {
          acc[i][j] = MFMA(ah[i], bl[j], acc[i][j]);
          acc[i][j] = MFMA(al[i], bh[j], acc[i][j]);
        }
    }
    __syncthreads();
  }
}

// ---------------------------------------------------------------------------
// QKV projection. grid (32, 6, 3): z=0 -> Q(hi,lo), z=1 -> K(hi,lo), z=2 -> V.
// Outputs in [B,H,T,D] layout.
// ---------------------------------------------------------------------------
__global__ __launch_bounds__(256) void qkv_gemm(
    const __hip_bfloat16* __restrict__ Xhi, const __hip_bfloat16* __restrict__ Xlo,
    const __hip_bfloat16* __restrict__ WqThi, const __hip_bfloat16* __restrict__ WqTlo,
    const __hip_bfloat16* __restrict__ WkThi, const __hip_bfloat16* __restrict__ WkTlo,
    const __hip_bfloat16* __restrict__ WvThi,
    __hip_bfloat16* __restrict__ Qhi, __hip_bfloat16* __restrict__ Qlo,
    __hip_bfloat16* __restrict__ Khi, __hip_bfloat16* __restrict__ Klo,
    __hip_bfloat16* __restrict__ V) {
  __shared__ __align__(16) short lds[16384];
  const int z = blockIdx.z;
  const bool lo = (z < 2);
  const __hip_bfloat16* Bhi = (z == 0) ? WqThi : (z == 1) ? WkThi : WvThi;
  const __hip_bfloat16* Blo = (z == 0) ? WqTlo : WkTlo;
  const int m0 = blockIdx.x * 128, n0 = blockIdx.y * 128;

  f32x4 acc[4][4];
#pragma unroll
  for (int i = 0; i < 4; ++i)
#pragma unroll
    for (int j = 0; j < 4; ++j) acc[i][j] = f32x4{0.f, 0.f, 0.f, 0.f};

  gemm128_hilo(Xhi, Xlo, Bhi, Blo, lo, m0, n0, lds, acc);

  const int tid = threadIdx.x, w = tid >> 6, l = tid & 63;
  const int wr = w >> 1, wc = w & 1;
#pragma unroll
  for (int i = 0; i < 4; ++i) {
#pragma unroll
    for (int j = 0; j < 4; ++j) {
#pragma unroll
      for (int r = 0; r < 4; ++r) {
        const int m = m0 + (wr << 6) + (i << 4) + ((l >> 4) << 2) + r;
        const int n = n0 + (wc << 6) + (j << 4) + (l & 15);
        const float v = acc[i][j][r];
        const int b = m >> 11, t = m & 2047, h = n >> 6, d = n & 63;
        const size_t idx = (((size_t)(b * Hh + h)) * Tt + t) * Dd + d;
        if (z == 2) {
          V[idx] = __float2bfloat16(v);
        } else {
          short hbits = f2bfbits(v);
          short lbits = f2bfbits(v - bf2f(hbits));
          if (z == 0) { ((short*)Qhi)[idx] = hbits; ((short*)Qlo)[idx] = lbits; }
          else        { ((short*)Khi)[idx] = hbits; ((short*)Klo)[idx] = lbits; }
        }
      }
    }
  }
}

// ---------------------------------------------------------------------------
// Output projection: out[M,C] (f32) = O[M,C](bf16) * LT[C,C]^T(bf16). grid(32,6)
// ---------------------------------------------------------------------------
__global__ __launch_bounds__(256) void proj_gemm(
    const __hip_bfloat16* __restrict__ O, const __hip_bfloat16* __restrict__ LT,
    float* __restrict__ out) {
  __shared__ __align__(16) short lds[8192];
  const int m0 = blockIdx.x * 128, n0 = blockIdx.y * 128;
  f32x4 acc[4][4];
#pragma unroll
  for (int i = 0; i < 4; ++i)
#pragma unroll
    for (int j = 0; j < 4; ++j) acc[i][j] = f32x4{0.f, 0.f, 0.f, 0.f};

  gemm128_core(O, LT, m0, n0, lds, lds + 4096, acc);

  const int tid = threadIdx.x, w = tid >> 6, l = tid & 63;
  const int wr = w >> 1, wc = w & 1;
#pragma unroll
  for (int i = 0; i < 4; ++i)
#pragma unroll
    for (int j = 0; j < 4; ++j)
#pragma unroll
      for (int r = 0; r < 4; ++r) {
        const int m = m0 + (wr << 6) + (i << 4) + ((l >> 4) << 2) + r;
        const int n = n0 + (wc << 6) + (j << 4) + (l & 15);
        out[(size_t)m * Cc + n] = acc[i][j][r];
      }
}

// ---------------------------------------------------------------------------
// V [BH][T][D] -> VT [BH][D][T].  grid (32, 24), 256 threads.
// ---------------------------------------------------------------------------
__global__ __launch_bounds__(256) void transpose_v(
    const __hip_bfloat16* __restrict__ V, __hip_bfloat16* __restrict__ VT) {
  __shared__ __align__(16) short tile[64][72];
  const int t0 = blockIdx.x * 64, bh = blockIdx.y;
  const __hip_bfloat16* src = V + (size_t)bh * Tt * Dd;
  __hip_bfloat16* dst = VT + (size_t)bh * Dd * Tt;
  const int tid = threadIdx.x;
  const int rr = tid >> 3;
  const int cc = (tid & 7) << 3;
#pragma unroll
  for (int it = 0; it < 2; ++it) {
    const int r = rr + it * 32;
    *reinterpret_cast<s16x8*>(&tile[r][cc]) =
        *reinterpret_cast<const s16x8*>(src + (size_t)(t0 + r) * Dd + cc);
  }
  __syncthreads();
#pragma unroll
  for (int it = 0; it < 2; ++it) {
    const int d = rr + it * 32;
    s16x8 o;
#pragma unroll
    for (int j = 0; j < 8; ++j) o[j] = tile[cc + j][d];
    *reinterpret_cast<s16x8*>(dst + (size_t)d * Tt + t0 + cc) = o;
  }
}

// ---------------------------------------------------------------------------
// Causal flash attention. grid (T/64, BH), 128 threads (2 waves).
// Wave owns 32 q-rows. KV-tile = 64. Q kept in registers (hi+lo frags).
// K hi/lo and VT fragments loaded straight from global (L2-resident).
// Logits = 8 * (Qhi*Khi + Qhi*Klo + Qlo*Khi). Online softmax in registers.
// P relayout via per-wave-private LDS (no barriers anywhere).
// ---------------------------------------------------------------------------
__global__ __launch_bounds__(128) void attn_fwd(
    const __hip_bfloat16* __restrict__ Qhi, const __hip_bfloat16* __restrict__ Qlo,
    const __hip_bfloat16* __restrict__ Khi, const __hip_bfloat16* __restrict__ Klo,
    const __hip_bfloat16* __restrict__ VT, __hip_bfloat16* __restrict__ O) {
  __shared__ __align__(16) short pbuf[2][32 * 72];
  const int qb = blockIdx.x, bh = blockIdx.y;
  const int b = bh / Hh, h = bh % Hh;
  const int tid = threadIdx.x, w = tid >> 6, l = tid & 63;
  const int lr = l & 15, lg = l >> 4;
  const int q0w = qb * 64 + w * 32;
  const size_t hqk = (size_t)bh * Tt * Dd;
  const __hip_bfloat16* qhp = Qhi + hqk;
  const __hip_bfloat16* qlp = Qlo + hqk;
  const __hip_bfloat16* khp = Khi + hqk;
  const __hip_bfloat16* klp = Klo + hqk;
  const __hip_bfloat16* vtp = VT + (size_t)bh * Dd * Tt;
  short* myP = &pbuf[w][0];

  s16x8 qh[2][2], ql[2][2];
#pragma unroll
  for (int qf = 0; qf < 2; ++qf)
#pragma unroll
    for (int df = 0; df < 2; ++df) {
      const size_t off = (size_t)(q0w + qf * 16 + lr) * Dd + df * 32 + lg * 8;
      qh[qf][df] = *reinterpret_cast<const s16x8*>(qhp + off);
      ql[qf][df] = *reinterpret_cast<const s16x8*>(qlp + off);
    }

  f32x4 oacc[2][4];
  float mrow[2][4], lrow[2][4];
#pragma unroll
  for (int qf = 0; qf < 2; ++qf) {
#pragma unroll
    for (int df = 0; df < 4; ++df) oacc[qf][df] = f32x4{0.f, 0.f, 0.f, 0.f};
#pragma unroll
    for (int r = 0; r < 4; ++r) { mrow[qf][r] = -__builtin_inff(); lrow[qf][r] = 0.f; }
  }

  const int ktmax = (q0w + 31) >> 6;
  for (int kt = 0; kt <= ktmax; ++kt) {
    const int k0 = kt << 6;
    const bool dotmask = (k0 + 63) > q0w;

    f32x4 s[2][4];
#pragma unroll
    for (int qf = 0; qf < 2; ++qf)
#pragma unroll
      for (int kjf = 0; kjf < 4; ++kjf) s[qf][kjf] = f32x4{0.f, 0.f, 0.f, 0.f};
#pragma unroll
    for (int kjf = 0; kjf < 4; ++kjf) {
      const int krow = k0 + kjf * 16 + lr;
#pragma unroll
      for (int df = 0; df < 2; ++df) {
        const size_t off = (size_t)krow * Dd + df * 32 + lg * 8;
        const s16x8 kh = *reinterpret_cast<const s16x8*>(khp + off);
        const s16x8 kl = *reinterpret_cast<const s16x8*>(klp + off);
#pragma unroll
        for (int qf = 0; qf < 2; ++qf) {
          s[qf][kjf] = MFMA(qh[qf][df], kh, s[qf][kjf]);
          s[qf][kjf] = MFMA(ql[qf][df], kh, s[qf][kjf]);
          s[qf][kjf] = MFMA(qh[qf][df], kl, s[qf][kjf]);
        }
      }
    }

#pragma unroll
    for (int qf = 0; qf < 2; ++qf) {
#pragma unroll
      for (int r = 0; r < 4; ++r) {
        const int qi = q0w + qf * 16 + lg * 4 + r;
        float mx = -__builtin_inff();
#pragma unroll
        for (int kjf = 0; kjf < 4; ++kjf) {
          float v = s[qf][kjf][r] * 8.0f;
          if (dotmask && (k0 + kjf * 16 + lr) > qi) v = -__builtin_inff();
          s[qf][kjf][r] = v;
          mx = fmaxf(mx, v);
        }
        mx = fmaxf(mx, __shfl_xor(mx, 1));
        mx = fmaxf(mx, __shfl_xor(mx, 2));
        mx = fmaxf(mx, __shfl_xor(mx, 4));
        mx = fmaxf(mx, __shfl_xor(mx, 8));
        const float mnew = fmaxf(mrow[qf][r], mx);
        const float sc = __expf(mrow[qf][r] - mnew);
        mrow[qf][r] = mnew;
        float ls = 0.f;
#pragma unroll
        for (int kjf = 0; kjf < 4; ++kjf) {
          const float p = __expf(s[qf][kjf][r] - mnew);
          s[qf][kjf][r] = p;
          ls += p;
        }
        ls += __shfl_xor(ls, 1);
        ls += __shfl_xor(ls, 2);
        ls += __shfl_xor(ls, 4);
        ls += __shfl_xor(ls, 8);
        lrow[qf][r] = lrow[qf][r] * sc + ls;
#pragma unroll
        for (int df = 0; df < 4; ++df) oacc[qf][df][r] *= sc;
      }
    }

#pragma unroll
    for (int qf = 0; qf < 2; ++qf)
#pragma unroll
      for (int kjf = 0; kjf < 4; ++kjf)
#pragma unroll
        for (int r = 0; r < 4; ++r)
          myP[(qf * 16 + lg * 4 + r) * 72 + kjf * 16 + lr] = f2bfbits(s[qf][kjf][r]);

#pragma unroll
    for (int kf = 0; kf < 2; ++kf) {
      s16x8 pa[2];
#pragma unroll
      for (int qf = 0; qf < 2; ++qf)
        pa[qf] = *reinterpret_cast<const s16x8*>(myP + (qf * 16 + lr) * 72 + kf * 32 + lg * 8);
#pragma unroll
      for (int df = 0; df < 4; ++df) {
        const s16x8 bv = *reinterpret_cast<const s16x8*>(
            vtp + (size_t)(df * 16 + lr) * Tt + k0 + kf * 32 + lg * 8);
#pragma unroll
        for (int qf = 0; qf < 2; ++qf) oacc[qf][df] = MFMA(pa[qf], bv, oacc[qf][df]);
      }
    }
  }

#pragma unroll
  for (int qf = 0; qf < 2; ++qf)
#pragma unroll
    for (int df = 0; df < 4; ++df)
#pragma unroll
      for (int r = 0; r < 4; ++r) {
        const int t = q0w + qf * 16 + lg * 4 + r;
        const int dc = df * 16 + lr;
        O[((size_t)b * Tt + t) * Cc + h * Dd + dc] =
            __float2bfloat16(oacc[qf][df][r] / lrow[qf][r]);
      }
}

// ---------------------------------------------------------------------------
extern "C" void kernel_launch(void* const* d_in, const int* in_sizes, int n_in,
                              void* d_out, int out_size, void* d_ws, size_t ws_size,
                              hipStream_t stream) {
  (void)in_sizes; (void)n_in; (void)out_size; (void)ws_size;
  const float* x  = (const float*)d_in[0];
  const float* wq = (const float*)d_in[1];
  const float* wk = (const float*)d_in[2];
  const float* wv = (const float*)d_in[3];
  const float* lm = (const float*)d_in[4];
  float* out = (float*)d_out;
  __hip_bfloat16* ws = (__hip_bfloat16*)d_ws;

  const size_t WSZ = (size_t)Cc * Cc;   // 589824
  const size_t TSZ = (size_t)Mm * Cc;   // 3145728
  __hip_bfloat16* WqThi = ws;
  __hip_bfloat16* WqTlo = WqThi + WSZ;
  __hip_bfloat16* WkThi = WqTlo + WSZ;
  __hip_bfloat16* WkTlo = WkThi + WSZ;
  __hip_bfloat16* WvThi = WkTlo + WSZ;
  __hip_bfloat16* LThi  = WvThi + WSZ;
  __hip_bfloat16* Xhi   = LThi + WSZ;
  __hip_bfloat16* Xlo   = Xhi + TSZ;
  __hip_bfloat16* Qhi   = Xlo + TSZ;
  __hip_bfloat16* Qlo   = Qhi + TSZ;
  __hip_bfloat16* Khi   = Qlo + TSZ;
  __hip_bfloat16* Klo   = Khi + TSZ;
  __hip_bfloat16* Vb    = Klo + TSZ;
  __hip_bfloat16* VT    = Vb + TSZ;
  __hip_bfloat16* Ob    = Vb;          // V dead after transpose_v; reuse for O

  prep_x<<<dim3(Mm * Cc / (256 * 8)), 256, 0, stream>>>(x, Xhi, Xlo);
  prep_w<<<dim3(12, 12, 4), 256, 0, stream>>>(wq, wk, wv, lm,
                                              WqThi, WqTlo, WkThi, WkTlo, WvThi, LThi);
  qkv_gemm<<<dim3(32, 6, 3), 256, 0, stream>>>(Xhi, Xlo, WqThi, WqTlo, WkThi, WkTlo,
                                               WvThi, Qhi, Qlo, Khi, Klo, Vb);
  transpose_v<<<dim3(32, BH), 256, 0, stream>>>(Vb, VT);
  attn_fwd<<<dim3(32, BH), 128, 0, stream>>>(Qhi, Qlo, Khi, Klo, VT, Ob);
  proj_gemm<<<dim3(32, 6), 256, 0, stream>>>(Ob, LThi, out);
}

// Round 4
// 201.571 us; speedup vs baseline: 1.1528x; 1.1528x over previous
//
#include <hip/hip_runtime.h>
#include <hip/hip_bf16.h>

// ---------------------------------------------------------------------------
// MultiHeadedMaskedSelfAttention (B=2,T=2048,C=768,H=12,D=64).
// I/O: float32. Compute: bf16 MFMA with hi/lo compensation on the
// softmax-critical path (x->Q/K and Q.K^T), plain bf16 elsewhere.
// attn_fwd v3: round-2 wave body VERBATIM (known good); only the
// wave->rows mapping changed: 4-wave blocks pair q-blocks {x, 31-x}
// (flat per-block work) and grid is XCD-grouped (3 heads per XCD -> K/V
// L2-resident). grid 384 = 8 xcd * 3 bh * 16 x.
// ---------------------------------------------------------------------------

typedef float f32x4 __attribute__((ext_vector_type(4)));
typedef short s16x8 __attribute__((ext_vector_type(8)));

#define MFMA(a, b, c) __builtin_amdgcn_mfma_f32_16x16x32_bf16((a), (b), (c), 0, 0, 0)

constexpr int Bb = 2, Tt = 2048, Cc = 768, Hh = 12, Dd = 64;
constexpr int Mm = Bb * Tt;   // 4096
constexpr int BH = Bb * Hh;   // 24

__device__ __forceinline__ void gload16(const void* g, void* l) {
  __builtin_amdgcn_global_load_lds((const __attribute__((address_space(1))) void*)g,
                                   (__attribute__((address_space(3))) void*)l, 16, 0, 0);
}

__device__ __forceinline__ short f2bfbits(float f) {
  __hip_bfloat16 h = __float2bfloat16(f);
  return __builtin_bit_cast(short, h);
}
__device__ __forceinline__ float bf2f(short s) {
  __hip_bfloat16 h = __builtin_bit_cast(__hip_bfloat16, s);
  return __bfloat162float(h);
}

// ---------------------------------------------------------------------------
// prep_x: x f32 [4096][768] -> Xhi, Xlo bf16. grid(1536), 256 thr, 8 elts/thr.
// ---------------------------------------------------------------------------
__global__ __launch_bounds__(256) void prep_x(const float* __restrict__ x,
                                              __hip_bfloat16* __restrict__ xhi,
                                              __hip_bfloat16* __restrict__ xlo) {
  const size_t i = ((size_t)blockIdx.x * 256 + threadIdx.x) * 8;
  float4 a = *reinterpret_cast<const float4*>(x + i);
  float4 b = *reinterpret_cast<const float4*>(x + i + 4);
  float v[8] = {a.x, a.y, a.z, a.w, b.x, b.y, b.z, b.w};
  s16x8 hi, lo;
#pragma unroll
  for (int j = 0; j < 8; ++j) {
    short h = f2bfbits(v[j]);
    hi[j] = h;
    lo[j] = f2bfbits(v[j] - bf2f(h));
  }
  *reinterpret_cast<s16x8*>((short*)xhi + i) = hi;
  *reinterpret_cast<s16x8*>((short*)xlo + i) = lo;
}

// ---------------------------------------------------------------------------
// prep_w: f32 [768][768] -> transposed bf16. z=0: wq (hi+lo), z=1: wk (hi+lo),
// z=2: wv (hi), z=3: linear (hi). grid (12,12,4), 256 thr, 64x64 tiles.
// ---------------------------------------------------------------------------
__global__ __launch_bounds__(256) void prep_w(
    const float* __restrict__ s0, const float* __restrict__ s1,
    const float* __restrict__ s2, const float* __restrict__ s3,
    __hip_bfloat16* __restrict__ h0, __hip_bfloat16* __restrict__ l0,
    __hip_bfloat16* __restrict__ h1, __hip_bfloat16* __restrict__ l1,
    __hip_bfloat16* __restrict__ h2, __hip_bfloat16* __restrict__ h3) {
  const float* src;
  __hip_bfloat16 *dh, *dl = nullptr;
  switch (blockIdx.z) {
    case 0: src = s0; dh = h0; dl = l0; break;
    case 1: src = s1; dh = h1; dl = l1; break;
    case 2: src = s2; dh = h2; break;
    default: src = s3; dh = h3; break;
  }
  __shared__ float tile[64][65];
  const int r0 = blockIdx.y * 64, c0 = blockIdx.x * 64;
  const int tid = threadIdx.x;
  const int rr = tid >> 4, c4 = (tid & 15) * 4;
#pragma unroll
  for (int it = 0; it < 4; ++it) {
    float4 v = *reinterpret_cast<const float4*>(src + (size_t)(r0 + rr + it * 16) * Cc + c0 + c4);
    tile[rr + it * 16][c4 + 0] = v.x;
    tile[rr + it * 16][c4 + 1] = v.y;
    tile[rr + it * 16][c4 + 2] = v.z;
    tile[rr + it * 16][c4 + 3] = v.w;
  }
  __syncthreads();
#pragma unroll
  for (int it = 0; it < 2; ++it) {
    const int id = tid + it * 256;          // 0..511
    const int n = id >> 3, ch = (id & 7) * 8;
    s16x8 hi, lo;
#pragma unroll
    for (int j = 0; j < 8; ++j) {
      float v = tile[ch + j][n];
      short h = f2bfbits(v);
      hi[j] = h;
      lo[j] = f2bfbits(v - bf2f(h));
    }
    *reinterpret_cast<s16x8*>(dh + (size_t)(c0 + n) * Cc + r0 + ch) = hi;
    if (dl) *reinterpret_cast<s16x8*>(dl + (size_t)(c0 + n) * Cc + r0 + ch) = lo;
  }
}

// ---------------------------------------------------------------------------
// 128x128 GEMM cores. A[M,K] * Bt[N,K]^T, K=768, BK=32, 4 waves.
// ---------------------------------------------------------------------------
__device__ __forceinline__ void gemm128_core(const __hip_bfloat16* __restrict__ A,
                                             const __hip_bfloat16* __restrict__ Bt,
                                             int m0, int n0,
                                             short* ldsA, short* ldsB,
                                             f32x4 acc[4][4]) {
  const int tid = threadIdx.x;
  const int w = tid >> 6, l = tid & 63;
  const int wr = w >> 1, wc = w & 1;
  const int srow = l >> 2;
  const int scol = (l & 3) << 3;

  for (int kt = 0; kt < Cc / 32; ++kt) {
    const int kk = kt << 5;
#pragma unroll
    for (int i = 0; i < 2; ++i) {
      const int r = (w << 5) + (i << 4);
      gload16(A + (size_t)(m0 + r + srow) * Cc + kk + scol, ldsA + r * 32);
      gload16(Bt + (size_t)(n0 + r + srow) * Cc + kk + scol, ldsB + r * 32);
    }
    __syncthreads();
    s16x8 af[4], bfr[4];
#pragma unroll
    for (int i = 0; i < 4; ++i) {
      af[i]  = *reinterpret_cast<const s16x8*>(ldsA + ((wr << 6) + (i << 4) + (l & 15)) * 32 + ((l >> 4) << 3));
      bfr[i] = *reinterpret_cast<const s16x8*>(ldsB + ((wc << 6) + (i << 4) + (l & 15)) * 32 + ((l >> 4) << 3));
    }
#pragma unroll
    for (int i = 0; i < 4; ++i)
#pragma unroll
      for (int j = 0; j < 4; ++j)
        acc[i][j] = MFMA(af[i], bfr[j], acc[i][j]);
    __syncthreads();
  }
}

// hi/lo compensated: acc += Ahi*Bhi + (lo ? Ahi*Blo + Alo*Bhi : 0)
__device__ __forceinline__ void gemm128_hilo(
    const __hip_bfloat16* __restrict__ Ahi, const __hip_bfloat16* __restrict__ Alo,
    const __hip_bfloat16* __restrict__ Bhi, const __hip_bfloat16* __restrict__ Blo,
    bool lo, int m0, int n0, short* lds, f32x4 acc[4][4]) {
  short* ldsAh = lds;
  short* ldsAl = lds + 4096;
  short* ldsBh = lds + 8192;
  short* ldsBl = lds + 12288;
  const int tid = threadIdx.x;
  const int w = tid >> 6, l = tid & 63;
  const int wr = w >> 1, wc = w & 1;
  const int srow = l >> 2;
  const int scol = (l & 3) << 3;

  for (int kt = 0; kt < Cc / 32; ++kt) {
    const int kk = kt << 5;
#pragma unroll
    for (int i = 0; i < 2; ++i) {
      const int r = (w << 5) + (i << 4);
      const size_t aoff = (size_t)(m0 + r + srow) * Cc + kk + scol;
      const size_t boff = (size_t)(n0 + r + srow) * Cc + kk + scol;
      gload16(Ahi + aoff, ldsAh + r * 32);
      gload16(Bhi + boff, ldsBh + r * 32);
      if (lo) {
        gload16(Alo + aoff, ldsAl + r * 32);
        gload16(Blo + boff, ldsBl + r * 32);
      }
    }
    __syncthreads();
    s16x8 ah[4], bh[4], al[4], bl[4];
#pragma unroll
    for (int i = 0; i < 4; ++i) {
      const int ao = ((wr << 6) + (i << 4) + (l & 15)) * 32 + ((l >> 4) << 3);
      const int bo = ((wc << 6) + (i << 4) + (l & 15)) * 32 + ((l >> 4) << 3);
      ah[i] = *reinterpret_cast<const s16x8*>(ldsAh + ao);
      bh[i] = *reinterpret_cast<const s16x8*>(ldsBh + bo);
      if (lo) {
        al[i] = *reinterpret_cast<const s16x8*>(ldsAl + ao);
        bl[i] = *reinterpret_cast<const s16x8*>(ldsBl + bo);
      }
    }
#pragma unroll
    for (int i = 0; i < 4; ++i)
#pragma unroll
      for (int j = 0; j < 4; ++j)
        acc[i][j] = MFMA(ah[i], bh[j], acc[i][j]);
    if (lo) {
#pragma unroll
      for (int i = 0; i < 4; ++i)
#pragma unroll
        for (int j = 0; j < 4; ++j) {
          acc[i][j] = MFMA(ah[i], bl[j], acc[i][j]);
          acc[i][j] = MFMA(al[i], bh[j], acc[i][j]);
        }
    }
    __syncthreads();
  }
}

// ---------------------------------------------------------------------------
// QKV projection. grid (32, 6, 3): z=0 -> Q(hi,lo), z=1 -> K(hi,lo), z=2 -> V.
// Outputs in [B,H,T,D] layout.
// ---------------------------------------------------------------------------
__global__ __launch_bounds__(256) void qkv_gemm(
    const __hip_bfloat16* __restrict__ Xhi, const __hip_bfloat16* __restrict__ Xlo,
    const __hip_bfloat16* __restrict__ WqThi, const __hip_bfloat16* __restrict__ WqTlo,
    const __hip_bfloat16* __restrict__ WkThi, const __hip_bfloat16* __restrict__ WkTlo,
    const __hip_bfloat16* __restrict__ WvThi,
    __hip_bfloat16* __restrict__ Qhi, __hip_bfloat16* __restrict__ Qlo,
    __hip_bfloat16* __restrict__ Khi, __hip_bfloat16* __restrict__ Klo,
    __hip_bfloat16* __restrict__ V) {
  __shared__ __align__(16) short lds[16384];
  const int z = blockIdx.z;
  const bool lo = (z < 2);
  const __hip_bfloat16* Bhi = (z == 0) ? WqThi : (z == 1) ? WkThi : WvThi;
  const __hip_bfloat16* Blo = (z == 0) ? WqTlo : WkTlo;
  const int m0 = blockIdx.x * 128, n0 = blockIdx.y * 128;

  f32x4 acc[4][4];
#pragma unroll
  for (int i = 0; i < 4; ++i)
#pragma unroll
    for (int j = 0; j < 4; ++j) acc[i][j] = f32x4{0.f, 0.f, 0.f, 0.f};

  gemm128_hilo(Xhi, Xlo, Bhi, Blo, lo, m0, n0, lds, acc);

  const int tid = threadIdx.x, w = tid >> 6, l = tid & 63;
  const int wr = w >> 1, wc = w & 1;
#pragma unroll
  for (int i = 0; i < 4; ++i) {
#pragma unroll
    for (int j = 0; j < 4; ++j) {
#pragma unroll
      for (int r = 0; r < 4; ++r) {
        const int m = m0 + (wr << 6) + (i << 4) + ((l >> 4) << 2) + r;
        const int n = n0 + (wc << 6) + (j << 4) + (l & 15);
        const float v = acc[i][j][r];
        const int b = m >> 11, t = m & 2047, h = n >> 6, d = n & 63;
        const size_t idx = (((size_t)(b * Hh + h)) * Tt + t) * Dd + d;
        if (z == 2) {
          V[idx] = __float2bfloat16(v);
        } else {
          short hbits = f2bfbits(v);
          short lbits = f2bfbits(v - bf2f(hbits));
          if (z == 0) { ((short*)Qhi)[idx] = hbits; ((short*)Qlo)[idx] = lbits; }
          else        { ((short*)Khi)[idx] = hbits; ((short*)Klo)[idx] = lbits; }
        }
      }
    }
  }
}

// ---------------------------------------------------------------------------
// Output projection: out[M,C] (f32) = O[M,C](bf16) * LT[C,C]^T(bf16). grid(32,6)
// ---------------------------------------------------------------------------
__global__ __launch_bounds__(256) void proj_gemm(
    const __hip_bfloat16* __restrict__ O, const __hip_bfloat16* __restrict__ LT,
    float* __restrict__ out) {
  __shared__ __align__(16) short lds[8192];
  const int m0 = blockIdx.x * 128, n0 = blockIdx.y * 128;
  f32x4 acc[4][4];
#pragma unroll
  for (int i = 0; i < 4; ++i)
#pragma unroll
    for (int j = 0; j < 4; ++j) acc[i][j] = f32x4{0.f, 0.f, 0.f, 0.f};

  gemm128_core(O, LT, m0, n0, lds, lds + 4096, acc);

  const int tid = threadIdx.x, w = tid >> 6, l = tid & 63;
  const int wr = w >> 1, wc = w & 1;
#pragma unroll
  for (int i = 0; i < 4; ++i)
#pragma unroll
    for (int j = 0; j < 4; ++j)
#pragma unroll
      for (int r = 0; r < 4; ++r) {
        const int m = m0 + (wr << 6) + (i << 4) + ((l >> 4) << 2) + r;
        const int n = n0 + (wc << 6) + (j << 4) + (l & 15);
        out[(size_t)m * Cc + n] = acc[i][j][r];
      }
}

// ---------------------------------------------------------------------------
// V [BH][T][D] -> VT [BH][D][T].  grid (32, 24), 256 threads.
// ---------------------------------------------------------------------------
__global__ __launch_bounds__(256) void transpose_v(
    const __hip_bfloat16* __restrict__ V, __hip_bfloat16* __restrict__ VT) {
  __shared__ __align__(16) short tile[64][72];
  const int t0 = blockIdx.x * 64, bh = blockIdx.y;
  const __hip_bfloat16* src = V + (size_t)bh * Tt * Dd;
  __hip_bfloat16* dst = VT + (size_t)bh * Dd * Tt;
  const int tid = threadIdx.x;
  const int rr = tid >> 3;
  const int cc = (tid & 7) << 3;
#pragma unroll
  for (int it = 0; it < 2; ++it) {
    const int r = rr + it * 32;
    *reinterpret_cast<s16x8*>(&tile[r][cc]) =
        *reinterpret_cast<const s16x8*>(src + (size_t)(t0 + r) * Dd + cc);
  }
  __syncthreads();
#pragma unroll
  for (int it = 0; it < 2; ++it) {
    const int d = rr + it * 32;
    s16x8 o;
#pragma unroll
    for (int j = 0; j < 8; ++j) o[j] = tile[cc + j][d];
    *reinterpret_cast<s16x8*>(dst + (size_t)d * Tt + t0 + cc) = o;
  }
}

// ---------------------------------------------------------------------------
// Causal flash attention v3. grid (384) x 256 threads (4 waves).
// Block i: xcd = i&7 serves bh in {3*(i&7) .. +2}; x = (i>>3)&15.
// Waves 0,1 -> q-block x (halves 0,1); waves 2,3 -> q-block 31-x.
// Per-wave inner code is the round-2 (verified) body, q0w = qblk*64+half*32.
// ---------------------------------------------------------------------------
__global__ __launch_bounds__(256) void attn_fwd(
    const __hip_bfloat16* __restrict__ Qhi, const __hip_bfloat16* __restrict__ Qlo,
    const __hip_bfloat16* __restrict__ Khi, const __hip_bfloat16* __restrict__ Klo,
    const __hip_bfloat16* __restrict__ VT, __hip_bfloat16* __restrict__ O) {
  __shared__ __align__(16) short pbuf[4][32 * 72];
  const int i = blockIdx.x;
  const int g = i >> 3;                       // 0..47
  const int bh = (i & 7) * 3 + (g >> 4);      // 0..23
  const int x = g & 15;                       // 0..15
  const int b = bh / Hh, h = bh % Hh;
  const int tid = threadIdx.x, w = tid >> 6, l = tid & 63;
  const int lr = l & 15, lg = l >> 4;
  const int qblk = (w < 2) ? x : (31 - x);
  const int q0w = qblk * 64 + (w & 1) * 32;   // this wave's first q row
  const size_t hqk = (size_t)bh * Tt * Dd;
  const __hip_bfloat16* qhp = Qhi + hqk;
  const __hip_bfloat16* qlp = Qlo + hqk;
  const __hip_bfloat16* khp = Khi + hqk;
  const __hip_bfloat16* klp = Klo + hqk;
  const __hip_bfloat16* vtp = VT + (size_t)bh * Dd * Tt;
  short* myP = &pbuf[w][0];

  s16x8 qh[2][2], ql[2][2];
#pragma unroll
  for (int qf = 0; qf < 2; ++qf)
#pragma unroll
    for (int df = 0; df < 2; ++df) {
      const size_t off = (size_t)(q0w + qf * 16 + lr) * Dd + df * 32 + lg * 8;
      qh[qf][df] = *reinterpret_cast<const s16x8*>(qhp + off);
      ql[qf][df] = *reinterpret_cast<const s16x8*>(qlp + off);
    }

  f32x4 oacc[2][4];
  float mrow[2][4], lrow[2][4];
#pragma unroll
  for (int qf = 0; qf < 2; ++qf) {
#pragma unroll
    for (int df = 0; df < 4; ++df) oacc[qf][df] = f32x4{0.f, 0.f, 0.f, 0.f};
#pragma unroll
    for (int r = 0; r < 4; ++r) { mrow[qf][r] = -__builtin_inff(); lrow[qf][r] = 0.f; }
  }

  const int ktmax = (q0w + 31) >> 6;
  for (int kt = 0; kt <= ktmax; ++kt) {
    const int k0 = kt << 6;
    const bool dotmask = (k0 + 63) > q0w;

    f32x4 s[2][4];
#pragma unroll
    for (int qf = 0; qf < 2; ++qf)
#pragma unroll
      for (int kjf = 0; kjf < 4; ++kjf) s[qf][kjf] = f32x4{0.f, 0.f, 0.f, 0.f};
#pragma unroll
    for (int kjf = 0; kjf < 4; ++kjf) {
      const int krow = k0 + kjf * 16 + lr;
#pragma unroll
      for (int df = 0; df < 2; ++df) {
        const size_t off = (size_t)krow * Dd + df * 32 + lg * 8;
        const s16x8 kh = *reinterpret_cast<const s16x8*>(khp + off);
        const s16x8 kl = *reinterpret_cast<const s16x8*>(klp + off);
#pragma unroll
        for (int qf = 0; qf < 2; ++qf) {
          s[qf][kjf] = MFMA(qh[qf][df], kh, s[qf][kjf]);
          s[qf][kjf] = MFMA(ql[qf][df], kh, s[qf][kjf]);
          s[qf][kjf] = MFMA(qh[qf][df], kl, s[qf][kjf]);
        }
      }
    }

#pragma unroll
    for (int qf = 0; qf < 2; ++qf) {
#pragma unroll
      for (int r = 0; r < 4; ++r) {
        const int qi = q0w + qf * 16 + lg * 4 + r;
        float mx = -__builtin_inff();
#pragma unroll
        for (int kjf = 0; kjf < 4; ++kjf) {
          float v = s[qf][kjf][r] * 8.0f;
          if (dotmask && (k0 + kjf * 16 + lr) > qi) v = -__builtin_inff();
          s[qf][kjf][r] = v;
          mx = fmaxf(mx, v);
        }
        mx = fmaxf(mx, __shfl_xor(mx, 1));
        mx = fmaxf(mx, __shfl_xor(mx, 2));
        mx = fmaxf(mx, __shfl_xor(mx, 4));
        mx = fmaxf(mx, __shfl_xor(mx, 8));
        const float mnew = fmaxf(mrow[qf][r], mx);
        const float sc = __expf(mrow[qf][r] - mnew);
        mrow[qf][r] = mnew;
        float ls = 0.f;
#pragma unroll
        for (int kjf = 0; kjf < 4; ++kjf) {
          const float p = __expf(s[qf][kjf][r] - mnew);
          s[qf][kjf][r] = p;
          ls += p;
        }
        ls += __shfl_xor(ls, 1);
        ls += __shfl_xor(ls, 2);
        ls += __shfl_xor(ls, 4);
        ls += __shfl_xor(ls, 8);
        lrow[qf][r] = lrow[qf][r] * sc + ls;
#pragma unroll
        for (int df = 0; df < 4; ++df) oacc[qf][df][r] *= sc;
      }
    }

#pragma unroll
    for (int qf = 0; qf < 2; ++qf)
#pragma unroll
      for (int kjf = 0; kjf < 4; ++kjf)
#pragma unroll
        for (int r = 0; r < 4; ++r)
          myP[(qf * 16 + lg * 4 + r) * 72 + kjf * 16 + lr] = f2bfbits(s[qf][kjf][r]);

#pragma unroll
    for (int kf = 0; kf < 2; ++kf) {
      s16x8 pa[2];
#pragma unroll
      for (int qf = 0; qf < 2; ++qf)
        pa[qf] = *reinterpret_cast<const s16x8*>(myP + (qf * 16 + lr) * 72 + kf * 32 + lg * 8);
#pragma unroll
      for (int df = 0; df < 4; ++df) {
        const s16x8 bv = *reinterpret_cast<const s16x8*>(
            vtp + (size_t)(df * 16 + lr) * Tt + k0 + kf * 32 + lg * 8);
#pragma unroll
        for (int qf = 0; qf < 2; ++qf) oacc[qf][df] = MFMA(pa[qf], bv, oacc[qf][df]);
      }
    }
  }

#pragma unroll
  for (int qf = 0; qf < 2; ++qf)
#pragma unroll
    for (int df = 0; df < 4; ++df)
#pragma unroll
      for (int r = 0; r < 4; ++r) {
        const int t = q0w + qf * 16 + lg * 4 + r;
        const int dc = df * 16 + lr;
        O[((size_t)b * Tt + t) * Cc + h * Dd + dc] =
            __float2bfloat16(oacc[qf][df][r] / lrow[qf][r]);
      }
}

// ---------------------------------------------------------------------------
extern "C" void kernel_launch(void* const* d_in, const int* in_sizes, int n_in,
                              void* d_out, int out_size, void* d_ws, size_t ws_size,
                              hipStream_t stream) {
  (void)in_sizes; (void)n_in; (void)out_size; (void)ws_size;
  const float* x  = (const float*)d_in[0];
  const float* wq = (const float*)d_in[1];
  const float* wk = (const float*)d_in[2];
  const float* wv = (const float*)d_in[3];
  const float* lm = (const float*)d_in[4];
  float* out = (float*)d_out;
  __hip_bfloat16* ws = (__hip_bfloat16*)d_ws;

  const size_t WSZ = (size_t)Cc * Cc;   // 589824
  const size_t TSZ = (size_t)Mm * Cc;   // 3145728
  __hip_bfloat16* WqThi = ws;
  __hip_bfloat16* WqTlo = WqThi + WSZ;
  __hip_bfloat16* WkThi = WqTlo + WSZ;
  __hip_bfloat16* WkTlo = WkThi + WSZ;
  __hip_bfloat16* WvThi = WkTlo + WSZ;
  __hip_bfloat16* LThi  = WvThi + WSZ;
  __hip_bfloat16* Xhi   = LThi + WSZ;
  __hip_bfloat16* Xlo   = Xhi + TSZ;
  __hip_bfloat16* Qhi   = Xlo + TSZ;
  __hip_bfloat16* Qlo   = Qhi + TSZ;
  __hip_bfloat16* Khi   = Qlo + TSZ;
  __hip_bfloat16* Klo   = Khi + TSZ;
  __hip_bfloat16* Vb    = Klo + TSZ;
  __hip_bfloat16* VT    = Vb + TSZ;
  __hip_bfloat16* Ob    = Vb;          // V dead after transpose_v; reuse for O

  prep_x<<<dim3(Mm * Cc / (256 * 8)), 256, 0, stream>>>(x, Xhi, Xlo);
  prep_w<<<dim3(12, 12, 4), 256, 0, stream>>>(wq, wk, wv, lm,
                                              WqThi, WqTlo, WkThi, WkTlo, WvThi, LThi);
  qkv_gemm<<<dim3(32, 6, 3), 256, 0, stream>>>(Xhi, Xlo, WqThi, WqTlo, WkThi, WkTlo,
                                               WvThi, Qhi, Qlo, Khi, Klo, Vb);
  transpose_v<<<dim3(32, BH), 256, 0, stream>>>(Vb, VT);
  attn_fwd<<<dim3(384), 256, 0, stream>>>(Qhi, Qlo, Khi, Klo, VT, Ob);
  proj_gemm<<<dim3(32, 6), 256, 0, stream>>>(Ob, LThi, out);
}